// Round 1
// baseline (26912.335 us; speedup 1.0000x reference)
//
#include <hip/hip_runtime.h>
#include <hip/hip_fp16.h>
#include <math.h>

// Problem dims (fixed)
#define T_SEQ 4096
#define DIN   64
#define DM    1024
#define G4    4096              // 4*DM gate rows
#define LSTRIDE_W ((size_t)G4 * DM)   // per-layer Wih/Whh stride
#define LSTRIDE_B ((size_t)G4)        // per-layer bias stride

typedef unsigned long long u64;
typedef unsigned int u32;

__device__ __forceinline__ float sigmoidf_(float x) {
    return 1.0f / (1.0f + __expf(-x));
}
__device__ __forceinline__ float tanhf_(float x) {
    float ax = fabsf(x);
    float e  = __expf(-2.0f * ax);
    float t  = (1.0f - e) / (1.0f + e);
    return copysignf(t, x);
}
__device__ __forceinline__ float lrelu_(float x) {
    return x > 0.0f ? x : 0.01f * x;
}

// pack two fp32 -> one u32 of two f16 (v_cvt_pkrtz_f16_f32)
__device__ __forceinline__ u32 pk2_(float x, float y) {
    typedef __fp16 hv2 __attribute__((ext_vector_type(2)));
    union { hv2 h; u32 u; } c;
    c.h = __builtin_amdgcn_cvt_pkrtz(x, y);
    return c.u;
}
// single f32 -> f16 with the SAME rounding (RTZ) as pk2_, stored as b16.
__device__ __forceinline__ void st_h16_(void* p, float x) {
    union { u32 u; __fp16 h[2]; } c;
    c.u = pk2_(x, x);
    *(__fp16*)p = c.h[0];
}
// fused f16-pair dot-accumulate: acc += a.x*b.x + a.y*b.y
#if __has_builtin(__builtin_amdgcn_fdot2)
__device__ __forceinline__ float d2a_(u32 a, u32 b, float acc) {
    typedef __fp16 hv2 __attribute__((ext_vector_type(2)));
    union { u32 u; hv2 h; } ua, ub;
    ua.u = a; ub.u = b;
    return __builtin_amdgcn_fdot2(ua.h, ub.h, acc, false);
}
#else
__device__ __forceinline__ float d2a_(u32 a, u32 b, float acc) {
    union { u32 u; __half2 h; } ua, ub;
    ua.u = a; ub.u = b;
    float2 fa = __half22float2(ua.h);
    float2 fb = __half22float2(ub.h);
    return acc + fa.x * fb.x + fa.y * fb.y;
}
#endif
__device__ __forceinline__ float dot8a_(uint4 q, uint4 h, float acc) {
    acc = d2a_(q.x, h.x, acc);
    acc = d2a_(q.y, h.y, acc);
    acc = d2a_(q.z, h.z, acc);
    acc = d2a_(q.w, h.w, acc);
    return acc;
}

// ---------------------------------------------------------------------------
// K1: x[t,d] = leaky_relu(sum_k inp[t,k]*W1[d,k] + b1[d]);  grid=4096, block=256
// ---------------------------------------------------------------------------
__global__ __launch_bounds__(256) void k_input(const float* __restrict__ inp,
                                               const float* __restrict__ W1,
                                               const float* __restrict__ b1,
                                               float* __restrict__ x) {
    __shared__ float s_in[DIN];
    const int t   = blockIdx.x;
    const int tid = threadIdx.x;
    if (tid < DIN) s_in[tid] = inp[(size_t)t * DIN + tid];
    __syncthreads();
#pragma unroll
    for (int q = 0; q < 4; q++) {
        const int d = tid + q * 256;
        const float4* wr = (const float4*)(W1 + (size_t)d * DIN);
        float acc = 0.0f;
#pragma unroll
        for (int e = 0; e < 16; e++) {
            float4 w = wr[e];
            acc += w.x * s_in[e * 4 + 0] + w.y * s_in[e * 4 + 1] +
                   w.z * s_in[e * 4 + 2] + w.w * s_in[e * 4 + 3];
        }
        acc += b1[d];
        x[(size_t)t * DM + d] = lrelu_(acc);
    }
}

// ---------------------------------------------------------------------------
// K2: xg[m,n] = sum_k x[m,k]*Wih0[n,k] + (bih0[n]+bhh0[n])
// 128x128 tile, BK=16, 256 threads, 8x8 per thread.
// ---------------------------------------------------------------------------
__global__ __launch_bounds__(256) void k_gemm(const float* __restrict__ A,
                                              const float* __restrict__ B,
                                              const float* __restrict__ bih,
                                              const float* __restrict__ bhh,
                                              float* __restrict__ C) {
    const int K = DM;
    __shared__ float As[16][132];
    __shared__ float Bs[16][132];
    const int tid = threadIdx.x;
    const int m0 = blockIdx.y * 128, n0 = blockIdx.x * 128;
    const int tx = tid & 15, ty = tid >> 4;
    const int lr = tid >> 1;
    const int lc = (tid & 1) * 8;

    float acc[8][8] = {};
    const float4* ag = (const float4*)(A + (size_t)(m0 + lr) * K + lc);
    const float4* bg = (const float4*)(B + (size_t)(n0 + lr) * K + lc);

    for (int k0 = 0; k0 < K; k0 += 16) {
        float4 a0 = ag[0], a1 = ag[1];
        float4 b0 = bg[0], b1v = bg[1];
        ag += 4; bg += 4;
        __syncthreads();
        As[lc + 0][lr] = a0.x; As[lc + 1][lr] = a0.y; As[lc + 2][lr] = a0.z; As[lc + 3][lr] = a0.w;
        As[lc + 4][lr] = a1.x; As[lc + 5][lr] = a1.y; As[lc + 6][lr] = a1.z; As[lc + 7][lr] = a1.w;
        Bs[lc + 0][lr] = b0.x; Bs[lc + 1][lr] = b0.y; Bs[lc + 2][lr] = b0.z; Bs[lc + 3][lr] = b0.w;
        Bs[lc + 4][lr] = b1v.x; Bs[lc + 5][lr] = b1v.y; Bs[lc + 6][lr] = b1v.z; Bs[lc + 7][lr] = b1v.w;
        __syncthreads();
#pragma unroll
        for (int k = 0; k < 16; k++) {
            float a[8], b[8];
            *(float4*)&a[0] = *(const float4*)&As[k][ty * 8 + 0];
            *(float4*)&a[4] = *(const float4*)&As[k][ty * 8 + 4];
            *(float4*)&b[0] = *(const float4*)&Bs[k][tx * 8 + 0];
            *(float4*)&b[4] = *(const float4*)&Bs[k][tx * 8 + 4];
#pragma unroll
            for (int i = 0; i < 8; i++)
#pragma unroll
                for (int j = 0; j < 8; j++)
                    acc[i][j] += a[i] * b[j];
        }
    }
    float bj[8];
#pragma unroll
    for (int j = 0; j < 8; j++) {
        int n = n0 + tx * 8 + j;
        bj[j] = bih[n] + bhh[n];
    }
#pragma unroll
    for (int i = 0; i < 8; i++) {
        float4 v0, v1;
        v0.x = acc[i][0] + bj[0]; v0.y = acc[i][1] + bj[1];
        v0.z = acc[i][2] + bj[2]; v0.w = acc[i][3] + bj[3];
        v1.x = acc[i][4] + bj[4]; v1.y = acc[i][5] + bj[5];
        v1.z = acc[i][6] + bj[6]; v1.w = acc[i][7] + bj[7];
        float* cp = C + (size_t)(m0 + ty * 8 + i) * G4 + n0 + tx * 8;
        *(float4*)(cp + 0) = v0;
        *(float4*)(cp + 4) = v1;
    }
}

// ---------------------------------------------------------------------------
// K3: fused 2-layer scan, R11 = merged single-barrier round + pipelined polls.
//
// R10 had 2 phases/step, each with its own MALL poll round-trip (~900cy) and
// its own __syncthreads -> ~6300cy/step, VALUBusy 20.7% (latency-bound).
// R11 changes (protocol semantics unchanged: tagged slots, demand-paced
// retry loops, NO far speculation -- R9 lesson):
//   1. ONE barrier per step: stage hst0[par] AND hst1[par] before a single
//      __syncthreads, then dot0 -> publish h0 -> dot1/dot2 -> publish h1.
//      (dot1 reads the SAME hst0[par] as dot0; hst1 data is a full step old.)
//   2. own-value bypass without the own0/own1 LDS round-trip: producer lane0
//      of wave s writes its f16 h directly into the NEXT parity staging
//      buffer (ds_write_b16, RTZ like pk2_ -> bit-identical numerics).
//      Write is post-barrier(t), readers are post-barrier(t+1): safe with a
//      single barrier. Thread tid==w simply skips staging its own slot.
//   3. h1 slot loads issued at loop TOP (before the blocking h0 poll): data
//      is ~1 step old, so a single tag-checked load burst almost always
//      hits; latency hidden under the h0 poll. Demand-loop fallback on miss.
//   4. h0 loads for step t+1 issued right after publishing our own h0(t)
//      (one-step demand issued early, NOT speculation: same tag t+1 we will
//      need, checked at next loop top, demand-loop fallback on miss). The
//      ~900cy MALL latency hides under dot1/dot2 + reduce + gates.
// Expected: ~6300 -> ~4000-4500 cy/step.
// ---------------------------------------------------------------------------
__global__ __launch_bounds__(256, 1) void k_scan2(
        const float* __restrict__ xg,     // T x 4096 layer-0 preacts
        const float* __restrict__ Wih1,
        const float* __restrict__ Whh0,
        const float* __restrict__ Whh1,
        const float* __restrict__ bih1,
        const float* __restrict__ bhh1,
        u64* sl0,                         // [2][1024] tagged h0 slots
        u64* sl1,                         // [2][1024] tagged h1 slots
        float* __restrict__ out) {
    const int tid = threadIdx.x;
    const int w   = blockIdx.x;
    const int wv  = tid >> 6;             // wave 0..3 == state index s
    const int ln  = tid & 63;             // lane
    const int rs  = tid >> 4;             // row slot 0..15
    const int ck  = tid & 15;             // k-chunk of 64
    const int s_i = rs >> 2;              // state (== wv)
    const int g_i = rs & 3;               // gate
    const int r   = g_i * DM + w * 4 + s_i;   // global gate row

    __shared__ uint4 wlds[3][4][8][64];   // 96 KB f16 weights (self-storage)
    __shared__ uint4 hst0[2][16][9];      // h0 staged (f16), parity dbuf
    __shared__ uint4 hst1[2][16][9];      // h1 staged (f16), parity dbuf

    // ---- prologue: pack f16 weights into LDS (self-storage) ----
    {
        const float* srcs[3] = { Whh0, Wih1, Whh1 };
#pragma unroll
        for (int m = 0; m < 3; m++) {
            const float4* gw = (const float4*)(srcs[m] + (size_t)r * DM + ck * 64);
#pragma unroll
            for (int e = 0; e < 8; e++) {
                float4 a = gw[e * 2 + 0];
                float4 b = gw[e * 2 + 1];
                uint4 q;
                q.x = pk2_(a.x, a.y); q.y = pk2_(a.z, a.w);
                q.z = pk2_(b.x, b.y); q.w = pk2_(b.z, b.w);
                wlds[m][wv][e][ln] = q;
            }
        }
    }
    // layer-1 gate biases: lane 0 of wave s holds b1s[g] for state s
    float b1s[4] = {0.f, 0.f, 0.f, 0.f};
    if (ln == 0) {
#pragma unroll
        for (int gg = 0; gg < 4; gg++)
            b1s[gg] = bih1[gg * DM + w * 4 + wv] + bhh1[gg * DM + w * 4 + wv];
    }
    __syncthreads();

    const int stc = tid >> 4;             // stage chunk for h[tid*4..+4)
    const int sto = tid & 15;             // u64 index within chunk row
    const bool notown = (tid != w);       // own slot is staged by lane0 b16 writes
    float c0 = 0.f, h0v = 0.f, c1 = 0.f, h1v = 0.f;

    float xgv_cur = 0.f;
    if (ck == 0) xgv_cur = xg[r];         // row t=0

    // carried early-issued h0 slot loads (for the NEXT step's staging)
    u64 a0 = 0, a1 = 0, a2 = 0, a3 = 0;

    for (int t = 0; t <= T_SEQ; t++) {
        const int par = t & 1;
        const u64* p1 = sl1 + (size_t)par * 1024 + tid * 4;

        // (1) h1 slot loads issued FIRST (data ~1 step old -> near-certain
        //     hit); latency hides under the h0 poll below.
        u64 d0 = 0, d1 = 0, d2 = 0, d3 = 0;
        if (t > 0 && notown) {
            d0 = __hip_atomic_load(p1 + 0, __ATOMIC_RELAXED, __HIP_MEMORY_SCOPE_AGENT);
            d1 = __hip_atomic_load(p1 + 1, __ATOMIC_RELAXED, __HIP_MEMORY_SCOPE_AGENT);
            d2 = __hip_atomic_load(p1 + 2, __ATOMIC_RELAXED, __HIP_MEMORY_SCOPE_AGENT);
            d3 = __hip_atomic_load(p1 + 3, __ATOMIC_RELAXED, __HIP_MEMORY_SCOPE_AGENT);
        }

        // (2) h0 staging: check the early-issued loads, demand-loop on miss
        if (t == 0) {
            ((u64*)&hst0[0][stc][0])[sto] = 0ull;
        } else if (notown) {
            const u32 want = (u32)t;
            bool ok = ((u32)(a0 >> 32) == want) & ((u32)(a1 >> 32) == want) &
                      ((u32)(a2 >> 32) == want) & ((u32)(a3 >> 32) == want);
            if (!ok) {
                const u64* p0 = sl0 + (size_t)par * 1024 + tid * 4;
                do {
                    a0 = __hip_atomic_load(p0 + 0, __ATOMIC_RELAXED, __HIP_MEMORY_SCOPE_AGENT);
                    a1 = __hip_atomic_load(p0 + 1, __ATOMIC_RELAXED, __HIP_MEMORY_SCOPE_AGENT);
                    a2 = __hip_atomic_load(p0 + 2, __ATOMIC_RELAXED, __HIP_MEMORY_SCOPE_AGENT);
                    a3 = __hip_atomic_load(p0 + 3, __ATOMIC_RELAXED, __HIP_MEMORY_SCOPE_AGENT);
                    ok = ((u32)(a0 >> 32) == want) & ((u32)(a1 >> 32) == want) &
                         ((u32)(a2 >> 32) == want) & ((u32)(a3 >> 32) == want);
                } while (!ok);
            }
            u32 q0 = pk2_(__uint_as_float((u32)a0), __uint_as_float((u32)a1));
            u32 q1 = pk2_(__uint_as_float((u32)a2), __uint_as_float((u32)a3));
            ((u64*)&hst0[par][stc][0])[sto] = ((u64)q1 << 32) | q0;
        }

        // (3) h1 staging: tags should already match (old data)
        if (t == 0) {
            ((u64*)&hst1[0][stc][0])[sto] = 0ull;
        } else if (notown) {
            const u32 want = (u32)t;
            bool ok = ((u32)(d0 >> 32) == want) & ((u32)(d1 >> 32) == want) &
                      ((u32)(d2 >> 32) == want) & ((u32)(d3 >> 32) == want);
            if (!ok) {
                do {
                    d0 = __hip_atomic_load(p1 + 0, __ATOMIC_RELAXED, __HIP_MEMORY_SCOPE_AGENT);
                    d1 = __hip_atomic_load(p1 + 1, __ATOMIC_RELAXED, __HIP_MEMORY_SCOPE_AGENT);
                    d2 = __hip_atomic_load(p1 + 2, __ATOMIC_RELAXED, __HIP_MEMORY_SCOPE_AGENT);
                    d3 = __hip_atomic_load(p1 + 3, __ATOMIC_RELAXED, __HIP_MEMORY_SCOPE_AGENT);
                    ok = ((u32)(d0 >> 32) == want) & ((u32)(d1 >> 32) == want) &
                         ((u32)(d2 >> 32) == want) & ((u32)(d3 >> 32) == want);
                } while (!ok);
            }
            u32 q0 = pk2_(__uint_as_float((u32)d0), __uint_as_float((u32)d1));
            u32 q1 = pk2_(__uint_as_float((u32)d2), __uint_as_float((u32)d3));
            ((u64*)&hst1[par][stc][0])[sto] = ((u64)q1 << 32) | q0;
        }
        __syncthreads();   // B1: the ONLY barrier per round

        // (4) dot0: Whh0 row r · h0[t-1]
        float acc0 = 0.f;
#pragma unroll
        for (int e = 0; e < 8; e++) {
            acc0 = dot8a_(wlds[0][wv][e][ln], hst0[par][ck][e], acc0);
        }
#pragma unroll
        for (int m = 1; m <= 8; m <<= 1) acc0 += __shfl_xor(acc0, m, 64);
        if (ck == 0) acc0 += xgv_cur;     // lanes 0,16,32,48 hold gate preacts

        // in-wave gather + gate math + publish (lane 0 of wave s = state s)
        {
            float pi = __shfl(acc0, 0, 64);
            float pf = __shfl(acc0, 16, 64);
            float pg = __shfl(acc0, 32, 64);
            float po = __shfl(acc0, 48, 64);
            if (ln == 0 && t < T_SEQ) {
                c0 = sigmoidf_(pf) * c0 + sigmoidf_(pi) * tanhf_(pg);
                h0v = sigmoidf_(po) * tanhf_(c0);
                // own-WG bypass: write f16 half directly into NEXT parity
                // staging buffer (read after B1 of t+1 -> safe).
                st_h16_((char*)&hst0[par ^ 1][w >> 4][0] + (w & 15) * 8 + wv * 2, h0v);
                u64 v = ((u64)(u32)(t + 1) << 32) | (u64)__float_as_uint(h0v);
                __hip_atomic_store(sl0 + (size_t)((t + 1) & 1) * 1024 + w * 4 + wv,
                                   v, __ATOMIC_RELAXED, __HIP_MEMORY_SCOPE_AGENT);
            }
        }

        // (5) early-issue the NEXT step's h0 slot loads: remote publishes are
        //     happening ~now; the ~900cy MALL latency hides under dot1/dot2.
        if (t < T_SEQ && notown) {
            const u64* p0n = sl0 + (size_t)((t + 1) & 1) * 1024 + tid * 4;
            a0 = __hip_atomic_load(p0n + 0, __ATOMIC_RELAXED, __HIP_MEMORY_SCOPE_AGENT);
            a1 = __hip_atomic_load(p0n + 1, __ATOMIC_RELAXED, __HIP_MEMORY_SCOPE_AGENT);
            a2 = __hip_atomic_load(p0n + 2, __ATOMIC_RELAXED, __HIP_MEMORY_SCOPE_AGENT);
            a3 = __hip_atomic_load(p0n + 3, __ATOMIC_RELAXED, __HIP_MEMORY_SCOPE_AGENT);
        }

        // (6) xg prefetch for t+1 (16 tiny loads/WG; off-chain)
        float xgv_next = 0.f;
        if (ck == 0 && t + 1 < T_SEQ) xgv_next = xg[(size_t)(t + 1) * G4 + r];

        // (7) dot1: Wih1 row r · h0[t-1];  dot2: Whh1 row r · h1[t-2]
        float acc1 = 0.f, acc2 = 0.f;
#pragma unroll
        for (int e = 0; e < 8; e++) {
            acc1 = dot8a_(wlds[1][wv][e][ln], hst0[par][ck][e], acc1);
            acc2 = dot8a_(wlds[2][wv][e][ln], hst1[par][ck][e], acc2);
        }
#pragma unroll
        for (int m = 1; m <= 8; m <<= 1) {
            acc1 += __shfl_xor(acc1, m, 64);
            acc2 += __shfl_xor(acc2, m, 64);
        }
        // in-wave gather + gate + publish for layer 1 (lane 0 of wave s)
        {
            float pi = __shfl(acc1, 0, 64)  + __shfl(acc2, 0, 64);
            float pf = __shfl(acc1, 16, 64) + __shfl(acc2, 16, 64);
            float pg = __shfl(acc1, 32, 64) + __shfl(acc2, 32, 64);
            float po = __shfl(acc1, 48, 64) + __shfl(acc2, 48, 64);
            if (ln == 0) {
                if (t > 0) {
                    pi += b1s[0]; pf += b1s[1]; pg += b1s[2]; po += b1s[3];
                    c1 = sigmoidf_(pf) * c1 + sigmoidf_(pi) * tanhf_(pg);
                    h1v = sigmoidf_(po) * tanhf_(c1);
                }
                if (t < T_SEQ) {
                    st_h16_((char*)&hst1[par ^ 1][w >> 4][0] + (w & 15) * 8 + wv * 2, h1v);
                    u64 v = ((u64)(u32)(t + 1) << 32) | (u64)__float_as_uint(h1v);
                    __hip_atomic_store(sl1 + (size_t)((t + 1) & 1) * 1024 + w * 4 + wv,
                                       v, __ATOMIC_RELAXED, __HIP_MEMORY_SCOPE_AGENT);
                }
            }
        }
        xgv_cur = xgv_next;
        // Hazard notes (single barrier):
        //  - hst0/hst1[par] stagers write pre-B1(t); dot readers post-B1(t);
        //    next write to the same parity is pre-B1(t+2), after B1(t+1). OK.
        //  - lane0 b16 own-writes target buffer par^1, post-B1(t); readers of
        //    that buffer are dots post-B1(t+1); prior readers of that buffer
        //    (dots of t-1) finished before B1(t). OK.
        //  - slot tags monotonically increase; early loads are tag-checked
        //    with demand-loop fallback -> no ordering assumptions.
    }

    if (ln == 0) {
        out[w * 4 + wv] = lrelu_(h1v);    // h1[T-1]
    }
}

// ---------------------------------------------------------------------------
extern "C" void kernel_launch(void* const* d_in, const int* in_sizes, int n_in,
                              void* d_out, int out_size, void* d_ws, size_t ws_size,
                              hipStream_t stream) {
    const float* inp = (const float*)d_in[0];   // 4096 x 64
    const float* W1  = (const float*)d_in[1];   // 1024 x 64
    const float* b1  = (const float*)d_in[2];   // 1024
    const float* Wih = (const float*)d_in[3];   // 2 x 4096 x 1024
    const float* Whh = (const float*)d_in[4];   // 2 x 4096 x 1024
    const float* bih = (const float*)d_in[5];   // 2 x 4096
    const float* bhh = (const float*)d_in[6];   // 2 x 4096
    float* out = (float*)d_out;                 // 1024

    // workspace layout
    float* x   = (float*)d_ws;                          // 4096*1024 f32
    float* xg  = x + (size_t)T_SEQ * DM;                // 4096*4096 f32
    u64*   sl0 = (u64*)(xg + (size_t)T_SEQ * G4);       // 2*1024 u64
    u64*   sl1 = sl0 + 2048;                            // 2*1024 u64
    (void)in_sizes; (void)n_in; (void)out_size; (void)ws_size;

    // Phase 1: input projection
    k_input<<<dim3(T_SEQ), dim3(256), 0, stream>>>(inp, W1, b1, x);

    // Phase 2: xg = x @ Wih0^T + (bih0+bhh0)
    k_gemm<<<dim3(32, 32), dim3(256), 0, stream>>>(x, Wih, bih, bhh, xg);

    // Phase 3: fused 2-layer scan (single-barrier merged round, pipelined polls)
    k_scan2<<<dim3(256), dim3(256), 0, stream>>>(
        xg, Wih + LSTRIDE_W, Whh, Whh + LSTRIDE_W,
        bih + LSTRIDE_B, bhh + LSTRIDE_B, sl0, sl1, out);
}

// Round 2
// 12545.362 us; speedup vs baseline: 2.1452x; 2.1452x over previous
//
#include <hip/hip_runtime.h>
#include <hip/hip_fp16.h>
#include <math.h>

// Problem dims (fixed)
#define T_SEQ 4096
#define DIN   64
#define DM    1024
#define G4    4096              // 4*DM gate rows
#define LSTRIDE_W ((size_t)G4 * DM)   // per-layer Wih/Whh stride
#define LSTRIDE_B ((size_t)G4)        // per-layer bias stride

typedef unsigned long long u64;
typedef unsigned int u32;

__device__ __forceinline__ float sigmoidf_(float x) {
    return 1.0f / (1.0f + __expf(-x));
}
__device__ __forceinline__ float tanhf_(float x) {
    float ax = fabsf(x);
    float e  = __expf(-2.0f * ax);
    float t  = (1.0f - e) / (1.0f + e);
    return copysignf(t, x);
}
__device__ __forceinline__ float lrelu_(float x) {
    return x > 0.0f ? x : 0.01f * x;
}

// pack two fp32 -> one u32 of two f16 (v_cvt_pkrtz_f16_f32)
__device__ __forceinline__ u32 pk2_(float x, float y) {
    typedef __fp16 hv2 __attribute__((ext_vector_type(2)));
    union { hv2 h; u32 u; } c;
    c.h = __builtin_amdgcn_cvt_pkrtz(x, y);
    return c.u;
}
// fused f16-pair dot-accumulate: acc += a.x*b.x + a.y*b.y
#if __has_builtin(__builtin_amdgcn_fdot2)
__device__ __forceinline__ float d2a_(u32 a, u32 b, float acc) {
    typedef __fp16 hv2 __attribute__((ext_vector_type(2)));
    union { u32 u; hv2 h; } ua, ub;
    ua.u = a; ub.u = b;
    return __builtin_amdgcn_fdot2(ua.h, ub.h, acc, false);
}
#else
__device__ __forceinline__ float d2a_(u32 a, u32 b, float acc) {
    union { u32 u; __half2 h; } ua, ub;
    ua.u = a; ub.u = b;
    float2 fa = __half22float2(ua.h);
    float2 fb = __half22float2(ub.h);
    return acc + fa.x * fb.x + fa.y * fb.y;
}
#endif
__device__ __forceinline__ float dot8a_(uint4 q, uint4 h, float acc) {
    acc = d2a_(q.x, h.x, acc);
    acc = d2a_(q.y, h.y, acc);
    acc = d2a_(q.z, h.z, acc);
    acc = d2a_(q.w, h.w, acc);
    return acc;
}

// ---------------------------------------------------------------------------
// K1: x[t,d] = leaky_relu(sum_k inp[t,k]*W1[d,k] + b1[d]);  grid=4096, block=256
// ---------------------------------------------------------------------------
__global__ __launch_bounds__(256) void k_input(const float* __restrict__ inp,
                                               const float* __restrict__ W1,
                                               const float* __restrict__ b1,
                                               float* __restrict__ x) {
    __shared__ float s_in[DIN];
    const int t   = blockIdx.x;
    const int tid = threadIdx.x;
    if (tid < DIN) s_in[tid] = inp[(size_t)t * DIN + tid];
    __syncthreads();
#pragma unroll
    for (int q = 0; q < 4; q++) {
        const int d = tid + q * 256;
        const float4* wr = (const float4*)(W1 + (size_t)d * DIN);
        float acc = 0.0f;
#pragma unroll
        for (int e = 0; e < 16; e++) {
            float4 w = wr[e];
            acc += w.x * s_in[e * 4 + 0] + w.y * s_in[e * 4 + 1] +
                   w.z * s_in[e * 4 + 2] + w.w * s_in[e * 4 + 3];
        }
        acc += b1[d];
        x[(size_t)t * DM + d] = lrelu_(acc);
    }
}

// ---------------------------------------------------------------------------
// K2: xg[m,n] = sum_k x[m,k]*Wih0[n,k] + (bih0[n]+bhh0[n])
// 128x128 tile, BK=16, 256 threads, 8x8 per thread.
// ---------------------------------------------------------------------------
__global__ __launch_bounds__(256) void k_gemm(const float* __restrict__ A,
                                              const float* __restrict__ B,
                                              const float* __restrict__ bih,
                                              const float* __restrict__ bhh,
                                              float* __restrict__ C) {
    const int K = DM;
    __shared__ float As[16][132];
    __shared__ float Bs[16][132];
    const int tid = threadIdx.x;
    const int m0 = blockIdx.y * 128, n0 = blockIdx.x * 128;
    const int tx = tid & 15, ty = tid >> 4;
    const int lr = tid >> 1;
    const int lc = (tid & 1) * 8;

    float acc[8][8] = {};
    const float4* ag = (const float4*)(A + (size_t)(m0 + lr) * K + lc);
    const float4* bg = (const float4*)(B + (size_t)(n0 + lr) * K + lc);

    for (int k0 = 0; k0 < K; k0 += 16) {
        float4 a0 = ag[0], a1 = ag[1];
        float4 b0 = bg[0], b1v = bg[1];
        ag += 4; bg += 4;
        __syncthreads();
        As[lc + 0][lr] = a0.x; As[lc + 1][lr] = a0.y; As[lc + 2][lr] = a0.z; As[lc + 3][lr] = a0.w;
        As[lc + 4][lr] = a1.x; As[lc + 5][lr] = a1.y; As[lc + 6][lr] = a1.z; As[lc + 7][lr] = a1.w;
        Bs[lc + 0][lr] = b0.x; Bs[lc + 1][lr] = b0.y; Bs[lc + 2][lr] = b0.z; Bs[lc + 3][lr] = b0.w;
        Bs[lc + 4][lr] = b1v.x; Bs[lc + 5][lr] = b1v.y; Bs[lc + 6][lr] = b1v.z; Bs[lc + 7][lr] = b1v.w;
        __syncthreads();
#pragma unroll
        for (int k = 0; k < 16; k++) {
            float a[8], b[8];
            *(float4*)&a[0] = *(const float4*)&As[k][ty * 8 + 0];
            *(float4*)&a[4] = *(const float4*)&As[k][ty * 8 + 4];
            *(float4*)&b[0] = *(const float4*)&Bs[k][tx * 8 + 0];
            *(float4*)&b[4] = *(const float4*)&Bs[k][tx * 8 + 4];
#pragma unroll
            for (int i = 0; i < 8; i++)
#pragma unroll
                for (int j = 0; j < 8; j++)
                    acc[i][j] += a[i] * b[j];
        }
    }
    float bj[8];
#pragma unroll
    for (int j = 0; j < 8; j++) {
        int n = n0 + tx * 8 + j;
        bj[j] = bih[n] + bhh[n];
    }
#pragma unroll
    for (int i = 0; i < 8; i++) {
        float4 v0, v1;
        v0.x = acc[i][0] + bj[0]; v0.y = acc[i][1] + bj[1];
        v0.z = acc[i][2] + bj[2]; v0.w = acc[i][3] + bj[3];
        v1.x = acc[i][4] + bj[4]; v1.y = acc[i][5] + bj[5];
        v1.z = acc[i][6] + bj[6]; v1.w = acc[i][7] + bj[7];
        float* cp = C + (size_t)(m0 + ty * 8 + i) * G4 + n0 + tx * 8;
        *(float4*)(cp + 0) = v0;
        *(float4*)(cp + 4) = v1;
    }
}

// ---------------------------------------------------------------------------
// K3: fused 2-layer scan, R12 = R10 skeleton (two phases, two barriers, SAME
// publish/poll points -> same half-round publish->poll gaps that made R10's
// first-poll hit rate high) + safe latency overlap only:
//   (i)  h0 slot loads for tag t+1 issued at B3(t)+eps (remote h0(t+1)
//        publishes happened ~mid-round t, before our B3). Checked at top of
//        round t+1, ~1100cy later -> MALL RT hidden on hit; fallback is
//        exactly R10's demand poll.
//   (ii) h1 slot loads for tag t issued at B1(t)+eps (partial hit rate;
//        check point and fallback = R10's phase-B poll).
//   (iii) Whh0 fragments in 32 VGPRs (pure self-storage) -> dot0 loses its
//        8 ds_read_b128. wlds[1..2] stay in LDS (VGPR headroom, and phase-B
//        dots are the hiding window for (i)).
// All retry loops pace with s_sleep(1): a miss can never become an unpaced
// spin (R9/R11 congestion lesson: miss-spin traffic saturates the MALL and
// slows the very propagation it waits for; FETCH_SIZE is the tell).
// ---------------------------------------------------------------------------
__global__ __launch_bounds__(256, 1) void k_scan2(
        const float* __restrict__ xg,     // T x 4096 layer-0 preacts
        const float* __restrict__ Wih1,
        const float* __restrict__ Whh0,
        const float* __restrict__ Whh1,
        const float* __restrict__ bih1,
        const float* __restrict__ bhh1,
        u64* sl0,                         // [2][1024] tagged h0 slots
        u64* sl1,                         // [2][1024] tagged h1 slots
        float* __restrict__ out) {
    const int tid = threadIdx.x;
    const int w   = blockIdx.x;
    const int wv  = tid >> 6;             // wave 0..3 == state index s
    const int ln  = tid & 63;             // lane
    const int rs  = tid >> 4;             // row slot 0..15
    const int ck  = tid & 15;             // k-chunk of 64
    const int s_i = rs >> 2;              // state (== wv)
    const int g_i = rs & 3;               // gate
    const int r   = g_i * DM + w * 4 + s_i;   // global gate row

    __shared__ uint4 wlds[3][4][8][64];   // 96 KB f16 weights (self-storage;
                                          // [0] unread now but keeps LDS size
                                          // -> 1 WG/CU exclusivity as in R10)
    __shared__ uint4 hst0[2][16][9];      // h0 staged (f16), parity dbuf
    __shared__ uint4 hst1[2][16][9];      // h1 staged (f16), parity dbuf
    __shared__ float own0[4], own1[4];    // own-WG h bypass (no global trip)

    // ---- prologue: pack f16 weights into LDS; Whh0 row also into VGPRs ----
    uint4 wr0[8];
    {
        const float* srcs[3] = { Whh0, Wih1, Whh1 };
#pragma unroll
        for (int m = 0; m < 3; m++) {
            const float4* gw = (const float4*)(srcs[m] + (size_t)r * DM + ck * 64);
#pragma unroll
            for (int e = 0; e < 8; e++) {
                float4 a = gw[e * 2 + 0];
                float4 b = gw[e * 2 + 1];
                uint4 q;
                q.x = pk2_(a.x, a.y); q.y = pk2_(a.z, a.w);
                q.z = pk2_(b.x, b.y); q.w = pk2_(b.z, b.w);
                wlds[m][wv][e][ln] = q;
                if (m == 0) wr0[e] = q;
            }
        }
    }
    // layer-1 gate biases: lane 0 of wave s holds b1s[g] for state s
    float b1s[4] = {0.f, 0.f, 0.f, 0.f};
    if (ln == 0) {
#pragma unroll
        for (int gg = 0; gg < 4; gg++)
            b1s[gg] = bih1[gg * DM + w * 4 + wv] + bhh1[gg * DM + w * 4 + wv];
    }
    if (tid < 4) { own0[tid] = 0.f; own1[tid] = 0.f; }
    __syncthreads();

    const int stc = tid >> 4;             // stage chunk for h[tid*4..+4)
    const int sto = tid & 15;             // u64 index within chunk row
    float c0 = 0.f, h0v = 0.f, c1 = 0.f, h1v = 0.f;

    float xgv_cur = 0.f;
    if (ck == 0) xgv_cur = xg[r];         // row t=0

    // early-issued h0 slot loads, carried across the loop back-edge
    u64 a0 = 0, a1 = 0, a2 = 0, a3 = 0;

    for (int t = 0; t <= T_SEQ; t++) {
        const int par = t & 1;

        // ================= Phase A: critical h0 chain =================
        if (t == 0) {
            ((u64*)&hst0[0][stc][0])[sto] = 0ull;
        } else if (tid == w) {
            u32 q0 = pk2_(own0[0], own0[1]);
            u32 q1 = pk2_(own0[2], own0[3]);
            ((u64*)&hst0[par][stc][0])[sto] = ((u64)q1 << 32) | q0;
        } else {
            const u32 want = (u32)t;
            // check the loads issued at B3(t-1); fallback = R10 demand poll
            bool ok = ((u32)(a0 >> 32) == want) & ((u32)(a1 >> 32) == want) &
                      ((u32)(a2 >> 32) == want) & ((u32)(a3 >> 32) == want);
            if (!ok) {
                const u64* p0 = sl0 + (size_t)par * 1024 + tid * 4;
                do {
                    __builtin_amdgcn_s_sleep(1);   // paced retry (anti-congestion)
                    a0 = __hip_atomic_load(p0 + 0, __ATOMIC_RELAXED, __HIP_MEMORY_SCOPE_AGENT);
                    a1 = __hip_atomic_load(p0 + 1, __ATOMIC_RELAXED, __HIP_MEMORY_SCOPE_AGENT);
                    a2 = __hip_atomic_load(p0 + 2, __ATOMIC_RELAXED, __HIP_MEMORY_SCOPE_AGENT);
                    a3 = __hip_atomic_load(p0 + 3, __ATOMIC_RELAXED, __HIP_MEMORY_SCOPE_AGENT);
                    ok = ((u32)(a0 >> 32) == want) & ((u32)(a1 >> 32) == want) &
                         ((u32)(a2 >> 32) == want) & ((u32)(a3 >> 32) == want);
                } while (!ok);
            }
            u32 q0 = pk2_(__uint_as_float((u32)a0), __uint_as_float((u32)a1));
            u32 q1 = pk2_(__uint_as_float((u32)a2), __uint_as_float((u32)a3));
            ((u64*)&hst0[par][stc][0])[sto] = ((u64)q1 << 32) | q0;
        }
        __syncthreads();   // B1: hst0[par] visible

        // early-issue h1 slot loads (tag t): remote publishes were ~end of
        // round t-1; partial hit -> latency partially hidden under dot0.
        const u64* p1 = sl1 + (size_t)par * 1024 + tid * 4;
        u64 d0 = 0, d1 = 0, d2 = 0, d3 = 0;
        if (t > 0 && tid != w) {
            d0 = __hip_atomic_load(p1 + 0, __ATOMIC_RELAXED, __HIP_MEMORY_SCOPE_AGENT);
            d1 = __hip_atomic_load(p1 + 1, __ATOMIC_RELAXED, __HIP_MEMORY_SCOPE_AGENT);
            d2 = __hip_atomic_load(p1 + 2, __ATOMIC_RELAXED, __HIP_MEMORY_SCOPE_AGENT);
            d3 = __hip_atomic_load(p1 + 3, __ATOMIC_RELAXED, __HIP_MEMORY_SCOPE_AGENT);
        }

        // dot0: Whh0 row r · h0[t-1]  (weights in VGPRs, no LDS reads on A-side)
        float acc0 = 0.f;
#pragma unroll
        for (int e = 0; e < 8; e++) {
            acc0 = dot8a_(wr0[e], hst0[par][ck][e], acc0);
        }
#pragma unroll
        for (int m = 1; m <= 8; m <<= 1) acc0 += __shfl_xor(acc0, m, 64);
        if (ck == 0) acc0 += xgv_cur;     // lanes 0,16,32,48 hold gate preacts

        // in-wave gather + gate math + publish (lane 0 of wave s = state s)
        {
            float pi = __shfl(acc0, 0, 64);
            float pf = __shfl(acc0, 16, 64);
            float pg = __shfl(acc0, 32, 64);
            float po = __shfl(acc0, 48, 64);
            if (ln == 0 && t < T_SEQ) {
                c0 = sigmoidf_(pf) * c0 + sigmoidf_(pi) * tanhf_(pg);
                h0v = sigmoidf_(po) * tanhf_(c0);
                own0[wv] = h0v;
                u64 v = ((u64)(u32)(t + 1) << 32) | (u64)__float_as_uint(h0v);
                __hip_atomic_store(sl0 + (size_t)((t + 1) & 1) * 1024 + w * 4 + wv,
                                   v, __ATOMIC_RELAXED, __HIP_MEMORY_SCOPE_AGENT);
            }
        }

        // xg prefetch for t+1 (16 tiny loads/WG; drains by next use, off-chain)
        float xgv_next = 0.f;
        if (ck == 0 && t + 1 < T_SEQ) xgv_next = xg[(size_t)(t + 1) * G4 + r];

        // ================= Phase B: shadow h1 work =================
        if (t == 0) {
            ((u64*)&hst1[0][stc][0])[sto] = 0ull;
        } else if (tid == w) {
            u32 q0 = pk2_(own1[0], own1[1]);
            u32 q1 = pk2_(own1[2], own1[3]);
            ((u64*)&hst1[par][stc][0])[sto] = ((u64)q1 << 32) | q0;
        } else {
            const u32 want = (u32)t;
            // check the early-issued loads; fallback = R10 demand poll (paced)
            bool ok = ((u32)(d0 >> 32) == want) & ((u32)(d1 >> 32) == want) &
                      ((u32)(d2 >> 32) == want) & ((u32)(d3 >> 32) == want);
            if (!ok) {
                do {
                    __builtin_amdgcn_s_sleep(1);
                    d0 = __hip_atomic_load(p1 + 0, __ATOMIC_RELAXED, __HIP_MEMORY_SCOPE_AGENT);
                    d1 = __hip_atomic_load(p1 + 1, __ATOMIC_RELAXED, __HIP_MEMORY_SCOPE_AGENT);
                    d2 = __hip_atomic_load(p1 + 2, __ATOMIC_RELAXED, __HIP_MEMORY_SCOPE_AGENT);
                    d3 = __hip_atomic_load(p1 + 3, __ATOMIC_RELAXED, __HIP_MEMORY_SCOPE_AGENT);
                    ok = ((u32)(d0 >> 32) == want) & ((u32)(d1 >> 32) == want) &
                         ((u32)(d2 >> 32) == want) & ((u32)(d3 >> 32) == want);
                } while (!ok);
            }
            u32 q0 = pk2_(__uint_as_float((u32)d0), __uint_as_float((u32)d1));
            u32 q1 = pk2_(__uint_as_float((u32)d2), __uint_as_float((u32)d3));
            ((u64*)&hst1[par][stc][0])[sto] = ((u64)q1 << 32) | q0;
        }
        __syncthreads();   // B3: hst1[par] visible

        // early-issue h0 slot loads for tag t+1: remote h0(t+1) publishes
        // happened ~mid-round t (before our B3). ~1100cy of dot1/dot2 +
        // gates + loop tail hide the MALL RT; checked at top of round t+1.
        if (t < T_SEQ && tid != w) {
            const u64* p0n = sl0 + (size_t)((t + 1) & 1) * 1024 + tid * 4;
            a0 = __hip_atomic_load(p0n + 0, __ATOMIC_RELAXED, __HIP_MEMORY_SCOPE_AGENT);
            a1 = __hip_atomic_load(p0n + 1, __ATOMIC_RELAXED, __HIP_MEMORY_SCOPE_AGENT);
            a2 = __hip_atomic_load(p0n + 2, __ATOMIC_RELAXED, __HIP_MEMORY_SCOPE_AGENT);
            a3 = __hip_atomic_load(p0n + 3, __ATOMIC_RELAXED, __HIP_MEMORY_SCOPE_AGENT);
        }

        // dot1: Wih1 row r · h0[t-1];  dot2: Whh1 row r · h1[t-2]
        float acc1 = 0.f, acc2 = 0.f;
#pragma unroll
        for (int e = 0; e < 8; e++) {
            acc1 = dot8a_(wlds[1][wv][e][ln], hst0[par][ck][e], acc1);
            acc2 = dot8a_(wlds[2][wv][e][ln], hst1[par][ck][e], acc2);
        }
#pragma unroll
        for (int m = 1; m <= 8; m <<= 1) {
            acc1 += __shfl_xor(acc1, m, 64);
            acc2 += __shfl_xor(acc2, m, 64);
        }
        // in-wave gather + gate + publish for layer 1 (lane 0 of wave s)
        {
            float pi = __shfl(acc1, 0, 64)  + __shfl(acc2, 0, 64);
            float pf = __shfl(acc1, 16, 64) + __shfl(acc2, 16, 64);
            float pg = __shfl(acc1, 32, 64) + __shfl(acc2, 32, 64);
            float po = __shfl(acc1, 48, 64) + __shfl(acc2, 48, 64);
            if (ln == 0) {
                if (t > 0) {
                    pi += b1s[0]; pf += b1s[1]; pg += b1s[2]; po += b1s[3];
                    c1 = sigmoidf_(pf) * c1 + sigmoidf_(pi) * tanhf_(pg);
                    h1v = sigmoidf_(po) * tanhf_(c1);
                }
                if (t < T_SEQ) {
                    own1[wv] = h1v;
                    u64 v = ((u64)(u32)(t + 1) << 32) | (u64)__float_as_uint(h1v);
                    __hip_atomic_store(sl1 + (size_t)((t + 1) & 1) * 1024 + w * 4 + wv,
                                       v, __ATOMIC_RELAXED, __HIP_MEMORY_SCOPE_AGENT);
                }
            }
        }
        xgv_cur = xgv_next;
        // Hazards: identical to R10 (barrier structure unchanged).
        // hst0/hst1 parity dbuf + B1/B3 separate all read/write pairs.
        // own0 write (post-B1, t) vs read (pre-B1, t+1): B3(t) intervenes.
        // own1 write (post-B3, t) vs read (pre-B3, t+1): B1(t+1) intervenes.
        // Early loads are tag-checked registers with demand fallback -> no
        // ordering assumptions added.
    }

    if (ln == 0) {
        out[w * 4 + wv] = lrelu_(h1v);    // h1[T-1]
    }
}

// ---------------------------------------------------------------------------
extern "C" void kernel_launch(void* const* d_in, const int* in_sizes, int n_in,
                              void* d_out, int out_size, void* d_ws, size_t ws_size,
                              hipStream_t stream) {
    const float* inp = (const float*)d_in[0];   // 4096 x 64
    const float* W1  = (const float*)d_in[1];   // 1024 x 64
    const float* b1  = (const float*)d_in[2];   // 1024
    const float* Wih = (const float*)d_in[3];   // 2 x 4096 x 1024
    const float* Whh = (const float*)d_in[4];   // 2 x 4096 x 1024
    const float* bih = (const float*)d_in[5];   // 2 x 4096
    const float* bhh = (const float*)d_in[6];   // 2 x 4096
    float* out = (float*)d_out;                 // 1024

    // workspace layout
    float* x   = (float*)d_ws;                          // 4096*1024 f32
    float* xg  = x + (size_t)T_SEQ * DM;                // 4096*4096 f32
    u64*   sl0 = (u64*)(xg + (size_t)T_SEQ * G4);       // 2*1024 u64
    u64*   sl1 = sl0 + 2048;                            // 2*1024 u64
    (void)in_sizes; (void)n_in; (void)out_size; (void)ws_size;

    // Phase 1: input projection
    k_input<<<dim3(T_SEQ), dim3(256), 0, stream>>>(inp, W1, b1, x);

    // Phase 2: xg = x @ Wih0^T + (bih0+bhh0)
    k_gemm<<<dim3(32, 32), dim3(256), 0, stream>>>(x, Wih, bih, bhh, xg);

    // Phase 3: fused 2-layer scan (R10 skeleton + safe early-issue overlap)
    k_scan2<<<dim3(256), dim3(256), 0, stream>>>(
        xg, Wih + LSTRIDE_W, Whh, Whh + LSTRIDE_W,
        bih + LSTRIDE_B, bhh + LSTRIDE_B, sl0, sl1, out);
}